// Round 1
// baseline (250.690 us; speedup 1.0000x reference)
//
#include <hip/hip_runtime.h>
#include <hip/hip_bf16.h>
#include <math.h>

// Problem constants
#define BB 2
#define MM 9          // 1 query + 8 supports
#define MS 8
#define DD 256
#define HW 2304       // 48*48
#define NCLS 4
#define OUTR 224

typedef float floatx4 __attribute__((ext_vector_type(4)));
typedef __bf16 bf16x8 __attribute__((ext_vector_type(8)));
typedef unsigned short ushortx8 __attribute__((ext_vector_type(8)));

// ---------------- Kernel 1: per-pixel L2 normalize over D, transpose to [pix][d], cast bf16 ----
// in : emb[bm][d][pix] fp32   (bm = b*9+m, 18 planes of 256x2304)
// out: normed[bm][pix][d] bf16
__global__ __launch_bounds__(256) void knorm(const float* __restrict__ emb,
                                             __hip_bfloat16* __restrict__ outp) {
    __shared__ float tile[256][33];   // [d][pix], +1 pad
    __shared__ float psum[8][32];
    __shared__ float sscale[32];
    const int bm   = blockIdx.y;
    const int pix0 = blockIdx.x * 32;
    const int tid  = threadIdx.x;
    const int pc = tid & 31;   // pixel lane for load
    const int dr = tid >> 5;   // 0..7

    const float* src = emb + (size_t)bm * DD * HW + pix0;
#pragma unroll
    for (int r = 0; r < 32; ++r) {
        int d = r * 8 + dr;                       // covers d = 0..255
        tile[d][pc] = src[(size_t)d * HW + pc];   // coalesced: 32 consecutive pix
    }
    __syncthreads();
    // sum of squares: thread (chunk=dr, pix=pc) sums 32 d's
    float ss = 0.f;
#pragma unroll
    for (int s = 0; s < 32; ++s) {
        float v = tile[dr * 32 + s][pc];
        ss += v * v;
    }
    psum[dr][pc] = ss;
    __syncthreads();
    if (tid < 32) {
        float t = 0.f;
#pragma unroll
        for (int c = 0; c < 8; ++c) t += psum[c][tid];
        sscale[tid] = 1.0f / fmaxf(sqrtf(t), 1e-12f);
    }
    __syncthreads();
    __hip_bfloat16* dst = outp + (size_t)bm * HW * DD + (size_t)pix0 * DD;
#pragma unroll
    for (int r = 0; r < 32; ++r) {
        float v = tile[tid][r] * sscale[r];          // bank: (tid+r)%32 conflict-free
        dst[(size_t)r * DD + tid] = __float2bfloat16(v);  // 512B contiguous per r
    }
}

// ---------------- Kernel 2: pack per-class mask bits -------------------------------------------
// pm[b][m][n][k] fp32 in {0,1}; class 0 replaced by background = (n1+n2+n3 == 0)
__global__ __launch_bounds__(256) void kmask(const float* __restrict__ pm,
                                             unsigned char* __restrict__ mb) {
    int idx = blockIdx.x * 256 + threadIdx.x;   // over BB*MS*HW = 36864
    if (idx >= BB * MS * HW) return;
    int k = idx % HW;
    int bm = idx / HW;
    const float* p = pm + (size_t)bm * NCLS * HW + k;
    float p1 = p[HW], p2 = p[2 * HW], p3 = p[3 * HW];
    unsigned char bits = 0;
    if (p1 + p2 + p3 == 0.0f) bits |= 1;   // background -> class 0
    if (p1 != 0.0f) bits |= 2;
    if (p2 != 0.0f) bits |= 4;
    if (p3 != 0.0f) bits |= 8;
    mb[idx] = bits;
}

// ---------------- Kernel 3: bf16 MFMA GEMM (Q @ S^T) + fused per-class masked max --------------
__device__ __forceinline__ void gld16(const unsigned short* g, unsigned short* l) {
    __builtin_amdgcn_global_load_lds((__attribute__((address_space(1))) void*)g,
                                     (__attribute__((address_space(3))) void*)l, 16, 0, 0);
}

// grid: (144 = m*18 + kt, 18 = row tile, 2 = b); block 256 (4 waves)
// A = normed[b][0]   (2304 x 256 bf16, row-major)  rows = query pixels
// B = normed[b][1+m] (2304 x 256 bf16, row-major)  rows = support pixels
// C[q,k] = dot(A_q, B_k); epilogue: per class n, max over tile cols k with mask bit n
__global__ __launch_bounds__(256) void kgemm(const unsigned short* __restrict__ normed,
                                             const unsigned char* __restrict__ maskbits,
                                             float* __restrict__ part) {
    __shared__ __attribute__((aligned(16))) unsigned short As[128 * 32];
    __shared__ __attribute__((aligned(16))) unsigned short Bs[128 * 32];
    __shared__ float redbuf[NCLS][128][2];

    const int ct = blockIdx.x;       // 0..143
    const int rt = blockIdx.y;       // 0..17
    const int b  = blockIdx.z;
    const int m  = ct / 18;          // support index 0..7
    const int kt = ct % 18;          // col tile within support

    const int tid  = threadIdx.x;
    const int lane = tid & 63;
    const int wave = tid >> 6;
    const int wr = wave >> 1, wc = wave & 1;
    const int lrow = lane & 15;
    const int lko  = (lane >> 4) * 8;

    const unsigned short* A  = normed + (size_t)(b * MM) * (HW * DD) + (size_t)(rt * 128) * DD;
    const unsigned short* Bp = normed + (size_t)(b * MM + 1 + m) * (HW * DD) + (size_t)(kt * 128) * DD;

    const int srow = tid >> 2;          // 0..63
    const int scol = (tid & 3) * 8;

    floatx4 zero = {0.f, 0.f, 0.f, 0.f};
    floatx4 acc[4][4];
#pragma unroll
    for (int i = 0; i < 4; ++i)
#pragma unroll
        for (int j = 0; j < 4; ++j) acc[i][j] = zero;

    unsigned short* AsW = As + wave * 512;   // wave-uniform LDS staging base
    unsigned short* BsW = Bs + wave * 512;

    for (int k0 = 0; k0 < DD; k0 += 32) {
        // global -> LDS, 16B/lane; LDS layout = linear row-major [128][32]
        gld16(A  + (size_t)srow * DD        + k0 + scol, AsW);
        gld16(A  + (size_t)(64 + srow) * DD + k0 + scol, AsW + 2048);
        gld16(Bp + (size_t)srow * DD        + k0 + scol, BsW);
        gld16(Bp + (size_t)(64 + srow) * DD + k0 + scol, BsW + 2048);
        __syncthreads();   // compiler emits vmcnt(0) drain before barrier

        bf16x8 af[4], bfr[4];
#pragma unroll
        for (int i = 0; i < 4; ++i) {
            af[i]  = __builtin_bit_cast(bf16x8, *(const ushortx8*)(As + (wr * 64 + i * 16 + lrow) * 32 + lko));
            bfr[i] = __builtin_bit_cast(bf16x8, *(const ushortx8*)(Bs + (wc * 64 + i * 16 + lrow) * 32 + lko));
        }
#pragma unroll
        for (int i = 0; i < 4; ++i)
#pragma unroll
            for (int j = 0; j < 4; ++j)
                acc[i][j] = __builtin_amdgcn_mfma_f32_16x16x32_bf16(af[i], bfr[j], acc[i][j], 0, 0, 0);
        __syncthreads();
    }

    // ---- epilogue: masked max ----
    // lane's 4 cols: wc*64 + j*16 + lrow (j=0..3); C/D map: col=lane&15, row=quad*4+reg
    const unsigned char* mbp = maskbits + ((size_t)b * MS + m) * HW + kt * 128 + wc * 64 + lrow;
    const int mj0 = mbp[0], mj1 = mbp[16], mj2 = mbp[32], mj3 = mbp[48];

#pragma unroll
    for (int n = 0; n < NCLS; ++n) {
#pragma unroll
        for (int i = 0; i < 4; ++i) {
#pragma unroll
            for (int r = 0; r < 4; ++r) {
                float v = -INFINITY;
                if ((mj0 >> n) & 1) v = fmaxf(v, acc[i][0][r]);
                if ((mj1 >> n) & 1) v = fmaxf(v, acc[i][1][r]);
                if ((mj2 >> n) & 1) v = fmaxf(v, acc[i][2][r]);
                if ((mj3 >> n) & 1) v = fmaxf(v, acc[i][3][r]);
                // reduce across the 16 cols held by the 16-lane group
                v = fmaxf(v, __shfl_xor(v, 1, 16));
                v = fmaxf(v, __shfl_xor(v, 2, 16));
                v = fmaxf(v, __shfl_xor(v, 4, 16));
                v = fmaxf(v, __shfl_xor(v, 8, 16));
                if (lrow == 0) {
                    int row = wr * 64 + i * 16 + (lane >> 4) * 4 + r;
                    redbuf[n][row][wc] = v;
                }
            }
        }
    }
    __syncthreads();
    // combine the two col-halves, write partials: part[b][ct][n][qglobal]
#pragma unroll
    for (int t = 0; t < 2; ++t) {
        int task = tid + t * 256;          // 512 tasks = 4 n * 128 rows
        int n = task >> 7, row = task & 127;
        float v = fmaxf(redbuf[n][row][0], redbuf[n][row][1]);
        part[(((size_t)b * 144 + ct) * NCLS + n) * HW + rt * 128 + row] = v;
    }
}

// ---------------- Kernel 4: reduce partials over the 144 col-tiles -----------------------------
__global__ __launch_bounds__(256) void kreduce(const float* __restrict__ part,
                                               float* __restrict__ logits) {
    int idx = blockIdx.x * 256 + threadIdx.x;   // 0 .. BB*NCLS*HW-1 = 18431
    if (idx >= BB * NCLS * HW) return;
    int q = idx % HW;
    int bn = idx / HW;          // b*4+n
    int b = bn >> 2, n = bn & 3;
    float v = -INFINITY;
    for (int ct = 0; ct < 144; ++ct)
        v = fmaxf(v, part[(((size_t)b * 144 + ct) * NCLS + n) * HW + q]);
    logits[(size_t)bn * HW + q] = v;
}

// ---------------- Kernel 5: bilinear 48 -> 224 (jax half-pixel semantics) + -inf fix on ch 0 ---
__global__ __launch_bounds__(256) void kresize(const float* __restrict__ logits,
                                               float* __restrict__ out) {
    int idx = blockIdx.x * 256 + threadIdx.x;   // BB*NCLS*224*224 = 401408
    if (idx >= BB * NCLS * OUTR * OUTR) return;
    int ox = idx % OUTR;
    int oy = (idx / OUTR) % OUTR;
    int bn = idx / (OUTR * OUTR);
    const float* src = logits + (size_t)bn * HW;
    const float inv = 48.0f / 224.0f;
    float sx = (ox + 0.5f) * inv - 0.5f;
    float sy = (oy + 0.5f) * inv - 0.5f;
    int x0 = (int)floorf(sx); float fx = sx - x0;
    int y0 = (int)floorf(sy); float fy = sy - y0;
    int x0c = min(max(x0, 0), 47), x1c = min(max(x0 + 1, 0), 47);
    int y0c = min(max(y0, 0), 47), y1c = min(max(y0 + 1, 0), 47);
    float v00 = src[y0c * 48 + x0c], v01 = src[y0c * 48 + x1c];
    float v10 = src[y1c * 48 + x0c], v11 = src[y1c * 48 + x1c];
    float v = (1.f - fy) * ((1.f - fx) * v00 + fx * v01) + fy * ((1.f - fx) * v10 + fx * v11);
    if ((bn & 3) == 0 && v == -INFINITY) v = 0.f;   // reference: ch0 -inf -> 0 after resize
    out[idx] = v;
}

// ---------------- launch ------------------------------------------------------------------------
extern "C" void kernel_launch(void* const* d_in, const int* in_sizes, int n_in,
                              void* d_out, int out_size, void* d_ws, size_t ws_size,
                              hipStream_t stream) {
    const float* emb = (const float*)d_in[0];   // (2,9,256,48,48) fp32
    const float* pm  = (const float*)d_in[1];   // (2,8,4,48,48) fp32
    float* out = (float*)d_out;                 // (2,4,224,224) fp32

    // workspace carve (≈31 MB)
    char* ws = (char*)d_ws;
    const size_t normed_bytes = (size_t)BB * MM * HW * DD * 2;        // 21,233,664
    const size_t mask_bytes   = (size_t)BB * MS * HW;                 // 36,864
    const size_t part_bytes   = (size_t)BB * 144 * NCLS * HW * 4;     // 10,616,832
    __hip_bfloat16* normed = (__hip_bfloat16*)(ws);
    unsigned char*  mb     = (unsigned char*)(ws + normed_bytes);
    float*          part   = (float*)(ws + normed_bytes + mask_bytes);
    float*          logits = (float*)(ws + normed_bytes + mask_bytes + part_bytes);

    knorm<<<dim3(HW / 32, BB * MM), 256, 0, stream>>>(emb, normed);
    kmask<<<(BB * MS * HW + 255) / 256, 256, 0, stream>>>(pm, mb);
    kgemm<<<dim3(144, 18, BB), 256, 0, stream>>>((const unsigned short*)normed, mb, part);
    kreduce<<<(BB * NCLS * HW + 255) / 256, 256, 0, stream>>>(part, logits);
    kresize<<<(BB * NCLS * OUTR * OUTR + 255) / 256, 256, 0, stream>>>(logits, out);
}

// Round 2
// 199.495 us; speedup vs baseline: 1.2566x; 1.2566x over previous
//
#include <hip/hip_runtime.h>
#include <hip/hip_bf16.h>
#include <math.h>

// Problem constants
#define BB 2
#define MM 9          // 1 query + 8 supports
#define MS 8
#define DD 256
#define HW 2304       // 48*48
#define NCLS 4
#define OUTR 224

typedef float floatx4 __attribute__((ext_vector_type(4)));
typedef __bf16 bf16x8 __attribute__((ext_vector_type(8)));
typedef unsigned short ushortx8 __attribute__((ext_vector_type(8)));

// ---------------- Kernel 1: per-pixel L2 normalize over D, transpose to [pix][d], cast bf16 ----
__global__ __launch_bounds__(256) void knorm(const float* __restrict__ emb,
                                             __hip_bfloat16* __restrict__ outp) {
    __shared__ float tile[256][33];   // [d][pix], +1 pad
    __shared__ float psum[8][32];
    __shared__ float sscale[32];
    const int bm   = blockIdx.y;
    const int pix0 = blockIdx.x * 32;
    const int tid  = threadIdx.x;
    const int pc = tid & 31;   // pixel lane for load
    const int dr = tid >> 5;   // 0..7

    const float* src = emb + (size_t)bm * DD * HW + pix0;
#pragma unroll
    for (int r = 0; r < 32; ++r) {
        int d = r * 8 + dr;
        tile[d][pc] = src[(size_t)d * HW + pc];
    }
    __syncthreads();
    float ss = 0.f;
#pragma unroll
    for (int s = 0; s < 32; ++s) {
        float v = tile[dr * 32 + s][pc];
        ss += v * v;
    }
    psum[dr][pc] = ss;
    __syncthreads();
    if (tid < 32) {
        float t = 0.f;
#pragma unroll
        for (int c = 0; c < 8; ++c) t += psum[c][tid];
        sscale[tid] = 1.0f / fmaxf(sqrtf(t), 1e-12f);
    }
    __syncthreads();
    __hip_bfloat16* dst = outp + (size_t)bm * HW * DD + (size_t)pix0 * DD;
#pragma unroll
    for (int r = 0; r < 32; ++r) {
        float v = tile[tid][r] * sscale[r];
        dst[(size_t)r * DD + tid] = __float2bfloat16(v);
    }
}

// ---------------- Kernel 2: pack per-class mask bits -------------------------------------------
__global__ __launch_bounds__(256) void kmask(const float* __restrict__ pm,
                                             unsigned char* __restrict__ mb) {
    int idx = blockIdx.x * 256 + threadIdx.x;   // over BB*MS*HW = 36864
    if (idx >= BB * MS * HW) return;
    int k = idx % HW;
    int bm = idx / HW;
    const float* p = pm + (size_t)bm * NCLS * HW + k;
    float p1 = p[HW], p2 = p[2 * HW], p3 = p[3 * HW];
    unsigned char bits = 0;
    if (p1 + p2 + p3 == 0.0f) bits |= 1;   // background -> class 0
    if (p1 != 0.0f) bits |= 2;
    if (p2 != 0.0f) bits |= 4;
    if (p3 != 0.0f) bits |= 8;
    mb[idx] = bits;
}

// ---------------- Kernel 3: bf16 MFMA GEMM (Q @ S^T) + fused per-class masked max --------------
__device__ __forceinline__ void gld16(const unsigned short* g, unsigned short* l) {
    __builtin_amdgcn_global_load_lds((__attribute__((address_space(1))) void*)g,
                                     (__attribute__((address_space(3))) void*)l, 16, 0, 0);
}

// LDS budget: staging As/Bs = 16 KB; epilogue red[2][32][132] fp32 = 33792 B. Union them.
#define REDSTRIDE 132
#define SMEM_BYTES (2 * 32 * REDSTRIDE * 4)   // 33792 >= 16384

// grid: (144 = m*18 + kt, 18 = row tile, 2 = b); block 256 (4 waves)
__global__ __launch_bounds__(256) void kgemm(const unsigned short* __restrict__ normed,
                                             const unsigned char* __restrict__ maskbits,
                                             float* __restrict__ part) {
    __shared__ __attribute__((aligned(16))) unsigned char smem[SMEM_BYTES];
    unsigned short* As = (unsigned short*)smem;
    unsigned short* Bs = As + 128 * 32;
    float* red = (float*)smem;

    const int ct = blockIdx.x;       // 0..143
    const int rt = blockIdx.y;       // 0..17
    const int b  = blockIdx.z;
    const int m  = ct / 18;          // support index 0..7
    const int kt = ct % 18;          // col tile within support

    const int tid  = threadIdx.x;
    const int lane = tid & 63;
    const int wave = tid >> 6;
    const int wr = wave >> 1, wc = wave & 1;
    const int lrow = lane & 15;
    const int quad = lane >> 4;      // 0..3, also the desired K-chunk g

    const unsigned short* A  = normed + (size_t)(b * MM) * (HW * DD) + (size_t)(rt * 128) * DD;
    const unsigned short* Bp = normed + (size_t)(b * MM + 1 + m) * (HW * DD) + (size_t)(kt * 128) * DD;

    // staging: lane handles (row=srow, chunk = (tid&3) ^ swz(srow)); XOR keeps the 64B
    // row-segment coalesced while making fragment reads bank-conflict-free.
    const int srow = tid >> 2;          // 0..63
    const int sswz = (srow ^ (srow >> 2)) & 3;
    const int scol = ((tid & 3) ^ sswz) * 8;

    // fragment-read chunk slot: cs = g ^ swz(row), row&15 == lrow
    const int rswz = (lrow ^ (lrow >> 2)) & 3;
    const int cs   = (quad ^ rswz) * 8;

    floatx4 zero = {0.f, 0.f, 0.f, 0.f};
    floatx4 acc[4][4];
#pragma unroll
    for (int i = 0; i < 4; ++i)
#pragma unroll
        for (int j = 0; j < 4; ++j) acc[i][j] = zero;

    unsigned short* AsW = As + wave * 512;   // wave-uniform LDS staging base
    unsigned short* BsW = Bs + wave * 512;

    for (int k0 = 0; k0 < DD; k0 += 32) {
        gld16(A  + (size_t)srow * DD        + k0 + scol, AsW);
        gld16(A  + (size_t)(64 + srow) * DD + k0 + scol, AsW + 2048);
        gld16(Bp + (size_t)srow * DD        + k0 + scol, BsW);
        gld16(Bp + (size_t)(64 + srow) * DD + k0 + scol, BsW + 2048);
        __syncthreads();

        bf16x8 af[4], bfr[4];
#pragma unroll
        for (int i = 0; i < 4; ++i) {
            af[i]  = __builtin_bit_cast(bf16x8, *(const ushortx8*)(As + (wr * 64 + i * 16 + lrow) * 32 + cs));
            bfr[i] = __builtin_bit_cast(bf16x8, *(const ushortx8*)(Bs + (wc * 64 + i * 16 + lrow) * 32 + cs));
        }
#pragma unroll
        for (int i = 0; i < 4; ++i)
#pragma unroll
            for (int j = 0; j < 4; ++j)
                acc[i][j] = __builtin_amdgcn_mfma_f32_16x16x32_bf16(af[i], bfr[j], acc[i][j], 0, 0, 0);
        __syncthreads();
    }

    // ---- epilogue v2: no cross-lane shuffles ----
    // lane's cols: wc*64 + j*16 + lrow ; rows: wr*64 + i*16 + quad*4 + r
    const unsigned char* mbp = maskbits + ((size_t)b * MS + m) * HW + kt * 128 + wc * 64 + lrow;
    const int mj0 = mbp[0], mj1 = mbp[16], mj2 = mbp[32], mj3 = mbp[48];
    const int col32 = wc * 16 + lrow;

#pragma unroll
    for (int p = 0; p < 2; ++p) {
        if (p) __syncthreads();      // pass2 of pair 0 done reading red
        bool bit[2][4];
#pragma unroll
        for (int nn = 0; nn < 2; ++nn) {
            int n = p * 2 + nn;
            bit[nn][0] = (mj0 >> n) & 1;
            bit[nn][1] = (mj1 >> n) & 1;
            bit[nn][2] = (mj2 >> n) & 1;
            bit[nn][3] = (mj3 >> n) & 1;
        }
#pragma unroll
        for (int nn = 0; nn < 2; ++nn) {
#pragma unroll
            for (int i = 0; i < 4; ++i) {
                floatx4 o;
#pragma unroll
                for (int r = 0; r < 4; ++r) {
                    float t0 = bit[nn][0] ? acc[i][0][r] : -INFINITY;
                    float t1 = bit[nn][1] ? acc[i][1][r] : -INFINITY;
                    float t2 = bit[nn][2] ? acc[i][2][r] : -INFINITY;
                    float t3 = bit[nn][3] ? acc[i][3][r] : -INFINITY;
                    o[r] = fmaxf(fmaxf(t0, t1), fmaxf(t2, t3));
                }
                int rowbase = wr * 64 + i * 16 + quad * 4;
                *(floatx4*)(red + ((size_t)(nn * 32 + col32)) * REDSTRIDE + rowbase) = o;
            }
        }
        __syncthreads();
        // pass 2: 256 tasks = 2 classes x 128 rows
        {
            int nn  = tid >> 7;
            int row = tid & 127;
            float v = -INFINITY;
#pragma unroll
            for (int c = 0; c < 32; ++c)
                v = fmaxf(v, red[((size_t)(nn * 32 + c)) * REDSTRIDE + row]);
            int n = p * 2 + nn;
            part[(((size_t)b * 144 + ct) * NCLS + n) * HW + rt * 128 + row] = v;
        }
    }
}

// ---------------- Kernel 4: reduce partials over the 144 col-tiles -----------------------------
__global__ __launch_bounds__(256) void kreduce(const float* __restrict__ part,
                                               float* __restrict__ logits) {
    int idx = blockIdx.x * 256 + threadIdx.x;   // 0 .. BB*NCLS*HW-1
    if (idx >= BB * NCLS * HW) return;
    int q = idx % HW;
    int bn = idx / HW;          // b*4+n
    int b = bn >> 2, n = bn & 3;
    float v = -INFINITY;
    for (int ct = 0; ct < 144; ++ct)
        v = fmaxf(v, part[(((size_t)b * 144 + ct) * NCLS + n) * HW + q]);
    logits[(size_t)bn * HW + q] = v;
}

// ---------------- Kernel 5: bilinear 48 -> 224 + -inf fix on ch 0 ------------------------------
__global__ __launch_bounds__(256) void kresize(const float* __restrict__ logits,
                                               float* __restrict__ out) {
    int idx = blockIdx.x * 256 + threadIdx.x;   // BB*NCLS*224*224
    if (idx >= BB * NCLS * OUTR * OUTR) return;
    int ox = idx % OUTR;
    int oy = (idx / OUTR) % OUTR;
    int bn = idx / (OUTR * OUTR);
    const float* src = logits + (size_t)bn * HW;
    const float inv = 48.0f / 224.0f;
    float sx = (ox + 0.5f) * inv - 0.5f;
    float sy = (oy + 0.5f) * inv - 0.5f;
    int x0 = (int)floorf(sx); float fx = sx - x0;
    int y0 = (int)floorf(sy); float fy = sy - y0;
    int x0c = min(max(x0, 0), 47), x1c = min(max(x0 + 1, 0), 47);
    int y0c = min(max(y0, 0), 47), y1c = min(max(y0 + 1, 0), 47);
    float v00 = src[y0c * 48 + x0c], v01 = src[y0c * 48 + x1c];
    float v10 = src[y1c * 48 + x0c], v11 = src[y1c * 48 + x1c];
    float v = (1.f - fy) * ((1.f - fx) * v00 + fx * v01) + fy * ((1.f - fx) * v10 + fx * v11);
    if ((bn & 3) == 0 && v == -INFINITY) v = 0.f;
    out[idx] = v;
}

// ---------------- launch ------------------------------------------------------------------------
extern "C" void kernel_launch(void* const* d_in, const int* in_sizes, int n_in,
                              void* d_out, int out_size, void* d_ws, size_t ws_size,
                              hipStream_t stream) {
    const float* emb = (const float*)d_in[0];   // (2,9,256,48,48) fp32
    const float* pm  = (const float*)d_in[1];   // (2,8,4,48,48) fp32
    float* out = (float*)d_out;                 // (2,4,224,224) fp32

    char* ws = (char*)d_ws;
    const size_t normed_bytes = (size_t)BB * MM * HW * DD * 2;
    const size_t mask_bytes   = (size_t)BB * MS * HW;
    const size_t part_bytes   = (size_t)BB * 144 * NCLS * HW * 4;
    __hip_bfloat16* normed = (__hip_bfloat16*)(ws);
    unsigned char*  mb     = (unsigned char*)(ws + normed_bytes);
    float*          part   = (float*)(ws + normed_bytes + mask_bytes);
    float*          logits = (float*)(ws + normed_bytes + mask_bytes + part_bytes);

    knorm<<<dim3(HW / 32, BB * MM), 256, 0, stream>>>(emb, normed);
    kmask<<<(BB * MS * HW + 255) / 256, 256, 0, stream>>>(pm, mb);
    kgemm<<<dim3(144, 18, BB), 256, 0, stream>>>((const unsigned short*)normed, mb, part);
    kreduce<<<(BB * NCLS * HW + 255) / 256, 256, 0, stream>>>(part, logits);
    kresize<<<(BB * NCLS * OUTR * OUTR + 255) / 256, 256, 0, stream>>>(logits, out);
}

// Round 3
// 143.069 us; speedup vs baseline: 1.7522x; 1.3944x over previous
//
#include <hip/hip_runtime.h>
#include <hip/hip_bf16.h>
#include <math.h>

// Problem constants
#define BB 2
#define MM 9          // 1 query + 8 supports
#define MS 8
#define DD 256
#define HW 2304       // 48*48
#define NCLS 4
#define OUTR 224

typedef float floatx4 __attribute__((ext_vector_type(4)));
typedef __bf16 bf16x8 __attribute__((ext_vector_type(8)));
typedef unsigned short ushortx8 __attribute__((ext_vector_type(8)));

// order-preserving float <-> uint encode for atomicMax
__device__ __forceinline__ unsigned enc_f(float f) {
    unsigned u = __float_as_uint(f);
    return (u & 0x80000000u) ? ~u : (u | 0x80000000u);
}
__device__ __forceinline__ float dec_f(unsigned k) {
    unsigned u = (k & 0x80000000u) ? (k & 0x7FFFFFFFu) : ~k;
    return __uint_as_float(u);
}

// ---------------- Kernel 1: per-pixel L2 normalize over D, transpose to [pix][d], cast bf16 ----
// Also zero-inits the encoded-logits buffer (key 0 < enc(-inf) = 0x007FFFFF).
__global__ __launch_bounds__(256) void knorm(const float* __restrict__ emb,
                                             __hip_bfloat16* __restrict__ outp,
                                             unsigned* __restrict__ enc_logits) {
    __shared__ float tile[256][33];   // [d][pix], +1 pad
    __shared__ float psum[8][32];
    __shared__ float sscale[32];
    const int bm   = blockIdx.y;
    const int pix0 = blockIdx.x * 32;
    const int tid  = threadIdx.x;
    const int pc = tid & 31;
    const int dr = tid >> 5;

    // fused init of encoded logits (BB*NCLS*HW = 18432 entries)
    int flat = (blockIdx.y * gridDim.x + blockIdx.x) * 256 + tid;
    if (flat < BB * NCLS * HW) enc_logits[flat] = 0u;

    const float* src = emb + (size_t)bm * DD * HW + pix0;
#pragma unroll
    for (int r = 0; r < 32; ++r) {
        int d = r * 8 + dr;
        tile[d][pc] = src[(size_t)d * HW + pc];
    }
    __syncthreads();
    float ss = 0.f;
#pragma unroll
    for (int s = 0; s < 32; ++s) {
        float v = tile[dr * 32 + s][pc];
        ss += v * v;
    }
    psum[dr][pc] = ss;
    __syncthreads();
    if (tid < 32) {
        float t = 0.f;
#pragma unroll
        for (int c = 0; c < 8; ++c) t += psum[c][tid];
        sscale[tid] = 1.0f / fmaxf(sqrtf(t), 1e-12f);
    }
    __syncthreads();
    __hip_bfloat16* dst = outp + (size_t)bm * HW * DD + (size_t)pix0 * DD;
#pragma unroll
    for (int r = 0; r < 32; ++r) {
        float v = tile[tid][r] * sscale[r];
        dst[(size_t)r * DD + tid] = __float2bfloat16(v);
    }
}

// ---------------- Kernel 2: bf16 MFMA GEMM + fused mask + per-class masked max + atomicMax -----
__device__ __forceinline__ void gld16(const unsigned short* g, unsigned short* l) {
    __builtin_amdgcn_global_load_lds((__attribute__((address_space(1))) void*)g,
                                     (__attribute__((address_space(3))) void*)l, 16, 0, 0);
}

#define BK 64
#define REDSTRIDE 132
// LDS: staging As+Bs = 2*128*64*2 = 32768 B; epilogue red[2][32][132] f32 = 33792 B (union)
#define SMEM_BYTES 33792

// grid: (144 = m*18 + kt, 18 = row tile, 2 = b); block 256 (4 waves)
__global__ __launch_bounds__(256, 4) void kgemm(const unsigned short* __restrict__ normed,
                                                const float* __restrict__ pm,
                                                unsigned* __restrict__ enc_logits) {
    __shared__ __attribute__((aligned(16))) unsigned char smem[SMEM_BYTES];
    unsigned short* As = (unsigned short*)smem;          // [128][64] row-major, chunk-swizzled
    unsigned short* Bs = As + 128 * 64;
    float* red = (float*)smem;                           // union (staging dead in epilogue)

    const int ct = blockIdx.x;       // 0..143
    const int rt = blockIdx.y;       // 0..17
    const int b  = blockIdx.z;
    const int m  = ct / 18;          // support index 0..7
    const int kt = ct % 18;          // col tile within support

    const int tid  = threadIdx.x;
    const int lane = tid & 63;
    const int wave = tid >> 6;
    const int wr = wave >> 1, wc = wave & 1;
    const int lrow = lane & 15;
    const int quad = lane >> 4;      // 0..3

    const unsigned short* A  = normed + (size_t)(b * MM) * (HW * DD) + (size_t)(rt * 128) * DD;
    const unsigned short* Bp = normed + (size_t)(b * MM + 1 + m) * (HW * DD) + (size_t)(kt * 128) * DD;

    // ---- fused mask bits: support pixels kt*128 + wc*64 + j*16 + lrow, classes via pm --------
    const float* pmB = pm + (size_t)(b * MS + m) * NCLS * HW;
    int mj[4];
#pragma unroll
    for (int j = 0; j < 4; ++j) {
        int kp = kt * 128 + wc * 64 + j * 16 + lrow;
        float p1 = pmB[HW + kp], p2 = pmB[2 * HW + kp], p3 = pmB[3 * HW + kp];
        mj[j] = ((p1 + p2 + p3 == 0.0f) ? 1 : 0) | (p1 != 0.0f ? 2 : 0) |
                (p2 != 0.0f ? 4 : 0) | (p3 != 0.0f ? 8 : 0);
    }

    // staging: lane l covers row r0+(l>>3), phys chunk p=l&7 holds logical chunk p^(row&7).
    // row&7 == l>>3 because r0 is a multiple of 8 -> logical chunk = (l&7)^(l>>3).
    const int srq  = lane >> 3;                  // row within 8-row group
    const int scol = ((lane & 7) ^ srq) * 8;     // logical chunk * 8 elems

    floatx4 zero = {0.f, 0.f, 0.f, 0.f};
    floatx4 acc[4][4];
#pragma unroll
    for (int i = 0; i < 4; ++i)
#pragma unroll
        for (int j = 0; j < 4; ++j) acc[i][j] = zero;

    for (int k0 = 0; k0 < DD; k0 += BK) {
#pragma unroll
        for (int q = 0; q < 4; ++q) {
            int row = wave * 32 + q * 8 + srq;
            gld16(A  + (size_t)row * DD + k0 + scol, As + (wave * 4 + q) * 512);
            gld16(Bp + (size_t)row * DD + k0 + scol, Bs + (wave * 4 + q) * 512);
        }
        __syncthreads();
#pragma unroll
        for (int kk = 0; kk < 2; ++kk) {
            bf16x8 af[4], bfr[4];
#pragma unroll
            for (int i = 0; i < 4; ++i) {
                int ar = wr * 64 + i * 16 + lrow;
                int br = wc * 64 + i * 16 + lrow;
                int pcA = (kk * 4 + quad) ^ (ar & 7);   // phys chunk (swizzled)
                int pcB = (kk * 4 + quad) ^ (br & 7);
                af[i]  = __builtin_bit_cast(bf16x8, *(const ushortx8*)(As + ar * 64 + pcA * 8));
                bfr[i] = __builtin_bit_cast(bf16x8, *(const ushortx8*)(Bs + br * 64 + pcB * 8));
            }
#pragma unroll
            for (int i = 0; i < 4; ++i)
#pragma unroll
                for (int j = 0; j < 4; ++j)
                    acc[i][j] = __builtin_amdgcn_mfma_f32_16x16x32_bf16(af[i], bfr[j], acc[i][j], 0, 0, 0);
        }
        __syncthreads();
    }

    // ---- epilogue: per-class masked max, LDS transpose-reduce, atomicMax to encoded logits ---
    // lane's cols: wc*64 + j*16 + lrow ; rows: wr*64 + i*16 + quad*4 + r
    const int col32 = wc * 16 + lrow;

#pragma unroll
    for (int p = 0; p < 2; ++p) {
        if (p) __syncthreads();
        bool bit[2][4];
#pragma unroll
        for (int nn = 0; nn < 2; ++nn) {
            int n = p * 2 + nn;
#pragma unroll
            for (int j = 0; j < 4; ++j) bit[nn][j] = (mj[j] >> n) & 1;
        }
#pragma unroll
        for (int nn = 0; nn < 2; ++nn) {
#pragma unroll
            for (int i = 0; i < 4; ++i) {
                floatx4 o;
#pragma unroll
                for (int r = 0; r < 4; ++r) {
                    float t0 = bit[nn][0] ? acc[i][0][r] : -INFINITY;
                    float t1 = bit[nn][1] ? acc[i][1][r] : -INFINITY;
                    float t2 = bit[nn][2] ? acc[i][2][r] : -INFINITY;
                    float t3 = bit[nn][3] ? acc[i][3][r] : -INFINITY;
                    o[r] = fmaxf(fmaxf(t0, t1), fmaxf(t2, t3));
                }
                int rowbase = wr * 64 + i * 16 + quad * 4;
                *(floatx4*)(red + ((size_t)(nn * 32 + col32)) * REDSTRIDE + rowbase) = o;
            }
        }
        __syncthreads();
        {
            int nn  = tid >> 7;
            int row = tid & 127;
            float v = -INFINITY;
#pragma unroll
            for (int c = 0; c < 32; ++c)
                v = fmaxf(v, red[((size_t)(nn * 32 + c)) * REDSTRIDE + row]);
            int n = p * 2 + nn;
            atomicMax(enc_logits + ((size_t)b * NCLS + n) * HW + rt * 128 + row, enc_f(v));
        }
    }
}

// ---------------- Kernel 3: bilinear 48 -> 224 (decode) + -inf fix on ch 0 ---------------------
__global__ __launch_bounds__(256) void kresize(const unsigned* __restrict__ enc_logits,
                                               float* __restrict__ out) {
    int idx = blockIdx.x * 256 + threadIdx.x;   // BB*NCLS*224*224
    if (idx >= BB * NCLS * OUTR * OUTR) return;
    int ox = idx % OUTR;
    int oy = (idx / OUTR) % OUTR;
    int bn = idx / (OUTR * OUTR);
    const unsigned* src = enc_logits + (size_t)bn * HW;
    const float inv = 48.0f / 224.0f;
    float sx = (ox + 0.5f) * inv - 0.5f;
    float sy = (oy + 0.5f) * inv - 0.5f;
    int x0 = (int)floorf(sx); float fx = sx - x0;
    int y0 = (int)floorf(sy); float fy = sy - y0;
    int x0c = min(max(x0, 0), 47), x1c = min(max(x0 + 1, 0), 47);
    int y0c = min(max(y0, 0), 47), y1c = min(max(y0 + 1, 0), 47);
    float v00 = dec_f(src[y0c * 48 + x0c]), v01 = dec_f(src[y0c * 48 + x1c]);
    float v10 = dec_f(src[y1c * 48 + x0c]), v11 = dec_f(src[y1c * 48 + x1c]);
    float v = (1.f - fy) * ((1.f - fx) * v00 + fx * v01) + fy * ((1.f - fx) * v10 + fx * v11);
    if ((bn & 3) == 0 && v == -INFINITY) v = 0.f;
    out[idx] = v;
}

// ---------------- launch ------------------------------------------------------------------------
extern "C" void kernel_launch(void* const* d_in, const int* in_sizes, int n_in,
                              void* d_out, int out_size, void* d_ws, size_t ws_size,
                              hipStream_t stream) {
    const float* emb = (const float*)d_in[0];   // (2,9,256,48,48) fp32
    const float* pm  = (const float*)d_in[1];   // (2,8,4,48,48) fp32
    float* out = (float*)d_out;                 // (2,4,224,224) fp32

    char* ws = (char*)d_ws;
    const size_t normed_bytes = (size_t)BB * MM * HW * DD * 2;   // 21,233,664
    __hip_bfloat16* normed = (__hip_bfloat16*)(ws);
    unsigned*       enc    = (unsigned*)(ws + normed_bytes);     // BB*NCLS*HW uints

    knorm<<<dim3(HW / 32, BB * MM), 256, 0, stream>>>(emb, normed, enc);
    kgemm<<<dim3(144, 18, BB), 256, 0, stream>>>((const unsigned short*)normed, pm, enc);
    kresize<<<(BB * NCLS * OUTR * OUTR + 255) / 256, 256, 0, stream>>>(enc, out);
}